// Round 9
// baseline (361.043 us; speedup 1.0000x reference)
//
#include <hip/hip_runtime.h>
#include <hip/hip_bf16.h>
#include <math.h>

// S,B,H,NH = 2048,4,1024,16; HD=64
constexpr int S_ = 2048, B_ = 4, H_ = 1024, NH_ = 16, HD_ = 64;

typedef __attribute__((ext_vector_type(8))) short short8;   // 8 bf16 (4 VGPRs)
typedef __attribute__((ext_vector_type(4))) short short4v;  // 4 bf16
typedef __attribute__((ext_vector_type(4))) float floatx4;  // MFMA C/D
typedef __attribute__((ext_vector_type(2))) unsigned uint2v;

static __device__ __forceinline__ short f2bf(float f) {
    union { float f; unsigned u; } v; v.f = f;
    unsigned r = v.u + 0x7FFFu + ((v.u >> 16) & 1u);  // RNE
    return (short)(r >> 16);
}

// pack two f32 -> one u32 of two bf16 (truncation), via v_perm_b32
static __device__ __forceinline__ unsigned pack_bf(float p0, float p1) {
    return __builtin_amdgcn_perm(__float_as_uint(p1), __float_as_uint(p0), 0x07060302u);
}

// async global->LDS; LDS dest = wave-uniform base + lane*size
static __device__ __forceinline__ void gl2lds16(const void* g, void* l) {
    __builtin_amdgcn_global_load_lds(
        (const __attribute__((address_space(1))) void*)g,
        (__attribute__((address_space(3))) void*)l, 16, 0, 0);
}
static __device__ __forceinline__ void gl2lds4(const void* g, void* l) {
    __builtin_amdgcn_global_load_lds(
        (const __attribute__((address_space(1))) void*)g,
        (__attribute__((address_space(3))) void*)l, 4, 0, 0);
}

// P-fragment redistribution (in-register, replaces Ps LDS round-trip).
static __device__ __forceinline__ short8 pswz(unsigned a0, unsigned a1,
                                              unsigned b0, unsigned b1) {
    uint2v r0 = __builtin_amdgcn_permlane32_swap(a0, b0, false, false);
    uint2v s0 = __builtin_amdgcn_permlane16_swap(r0.x, r0.y, false, false);
    uint2v r1 = __builtin_amdgcn_permlane32_swap(a1, b1, false, false);
    uint2v s1 = __builtin_amdgcn_permlane16_swap(r1.x, r1.y, false, false);
    union { unsigned u[4]; short8 s; } o;
    o.u[0] = s0.x;  // W0: t = dq*8 + {0,1}
    o.u[1] = s1.x;  // W1: t = dq*8 + {2,3}
    o.u[2] = s0.y;  // W2: t = dq*8 + {4,5}
    o.u[3] = s1.y;  // W3: t = dq*8 + {6,7}
    return o.s;
}

// ---------------------------------------------------------------------------
// fused fp32 -> bf16 convert for hidden / Wqkv / Wd
// ---------------------------------------------------------------------------
__global__ __launch_bounds__(256) void cvt3_kernel(
    const float* __restrict__ a, short* __restrict__ oa, int na,
    const float* __restrict__ b, short* __restrict__ ob, int nb,
    const float* __restrict__ c, short* __restrict__ oc, int nc)
{
    const int idx = blockIdx.x * 256 + threadIdx.x;
    const float* src; short* dst; int i;
    if (idx < na)            { src = a; dst = oa; i = idx; }
    else if (idx < na + nb)  { src = b; dst = ob; i = idx - na; }
    else                     { src = c; dst = oc; i = idx - na - nb; }
    const float4 v = ((const float4*)src)[i];
    short4v o = { (short)f2bf(v.x), (short)f2bf(v.y), (short)f2bf(v.z), (short)f2bf(v.w) };
    ((short4v*)dst)[i] = o;
}

// ---------------------------------------------------------------------------
// mask int32 -> keep-BITS, layout [b][tblk=32][q=2048] u64 (bit j of word =
// keep for t = tblk*64 + j). One wave per (b,q,tblk) via __ballot.
// ---------------------------------------------------------------------------
__global__ __launch_bounds__(256) void mask_bit_kernel(
    const int* __restrict__ m, unsigned long long* __restrict__ mb)
{
    const int wid  = blockIdx.x * 4 + (threadIdx.x >> 6);
    const int lane = threadIdx.x & 63;
    const int b   = wid >> 16;           // 2048 q * 32 tb = 65536 per b
    const int rem = wid & 65535;
    const int q   = rem >> 5;
    const int tb  = rem & 31;
    const int v = m[((size_t)b * S_ + q) * S_ + tb * 64 + lane];
    const unsigned long long w = __ballot(v == 0);   // keep where mask==0
    if (lane == 0) mb[((size_t)b * 32 + tb) * 2048 + q] = w;
}

// ---------------------------------------------------------------------------
// QKV GEMM v2: BK=32, 3 LDS buffers, depth-2 counted-vmcnt pipeline.
// ---------------------------------------------------------------------------
__global__ __launch_bounds__(256, 3) void gemm_qkv_mfma(
    const short* __restrict__ A, const short* __restrict__ Bw,
    const float* __restrict__ bias,
    short* __restrict__ Qb, short* __restrict__ Kb, short* __restrict__ Vb)
{
    constexpr int K = H_;  // 1024
    __shared__ __align__(16) short As[3 * 4096];
    __shared__ __align__(16) short Bs[3 * 4096];

    const int t = threadIdx.x;
    const int wave = t >> 6, lane = t & 63;
    const int l15 = lane & 15, quad = lane >> 4;
    const int wm = wave & 1, wn = wave >> 1;
    const int row0 = blockIdx.y * 128;
    const int col0 = blockIdx.x * 128;

    floatx4 acc[4][4];
#pragma unroll
    for (int mi = 0; mi < 4; ++mi)
#pragma unroll
        for (int ni = 0; ni < 4; ++ni)
            acc[mi][ni] = (floatx4){0.f, 0.f, 0.f, 0.f};

    const int c0 = wave * 128 + lane, c1 = c0 + 64;
    const int r0 = c0 >> 2, jg0 = (((c0 & 3) ^ (((r0 & 3) + ((r0 >> 2) & 3)) & 3))) * 8;
    const int r1 = c1 >> 2, jg1 = (((c1 & 3) ^ (((r1 & 3) + ((r1 >> 2) & 3)) & 3))) * 8;
    const int db0 = (wave * 128) * 8;
    const int db1 = db0 + 64 * 8;

    const short* Ar0 = A  + (size_t)(row0 + r0) * K + jg0;
    const short* Ar1 = A  + (size_t)(row0 + r1) * K + jg1;
    const short* Br0 = Bw + (size_t)(col0 + r0) * K + jg0;
    const short* Br1 = Bw + (size_t)(col0 + r1) * K + jg1;

    gl2lds16(Ar0, &As[db0]); gl2lds16(Ar1, &As[db1]);
    gl2lds16(Br0, &Bs[db0]); gl2lds16(Br1, &Bs[db1]);
    __builtin_amdgcn_sched_barrier(0);
    gl2lds16(Ar0 + 32, &As[4096 + db0]); gl2lds16(Ar1 + 32, &As[4096 + db1]);
    gl2lds16(Br0 + 32, &Bs[4096 + db0]); gl2lds16(Br1 + 32, &Bs[4096 + db1]);
    __builtin_amdgcn_sched_barrier(0);

    int bc = 0, bs = 2;
#pragma unroll 1
    for (int it = 0; it < 32; ++it) {
        if (it < 31) { asm volatile("s_waitcnt vmcnt(4)" ::: "memory"); }
        else         { asm volatile("s_waitcnt vmcnt(0)" ::: "memory"); }
        __builtin_amdgcn_s_barrier();
        __builtin_amdgcn_sched_barrier(0);

        if (it < 30) {
            const int ko = (it + 2) * 32;
            gl2lds16(Ar0 + ko, &As[bs * 4096 + db0]);
            gl2lds16(Ar1 + ko, &As[bs * 4096 + db1]);
            gl2lds16(Br0 + ko, &Bs[bs * 4096 + db0]);
            gl2lds16(Br1 + ko, &Bs[bs * 4096 + db1]);
        }
        __builtin_amdgcn_sched_barrier(0);

        const int bo = bc * 4096;
        short8 af[4], bfr[4];
#pragma unroll
        for (int mi = 0; mi < 4; ++mi) {
            const int R = wm * 64 + mi * 16 + l15;
            const int sel = quad ^ (((R & 3) + ((R >> 2) & 3)) & 3);
            af[mi] = *(const short8*)&As[bo + R * 32 + sel * 8];
        }
#pragma unroll
        for (int ni = 0; ni < 4; ++ni) {
            const int R = wn * 64 + ni * 16 + l15;
            const int sel = quad ^ (((R & 3) + ((R >> 2) & 3)) & 3);
            bfr[ni] = *(const short8*)&Bs[bo + R * 32 + sel * 8];
        }
        __builtin_amdgcn_s_setprio(1);
#pragma unroll
        for (int mi = 0; mi < 4; ++mi)
#pragma unroll
            for (int ni = 0; ni < 4; ++ni)
                acc[mi][ni] = __builtin_amdgcn_mfma_f32_16x16x32_bf16(
                    af[mi], bfr[ni], acc[mi][ni], 0, 0, 0);
        __builtin_amdgcn_s_setprio(0);

        bc = (bc == 2) ? 0 : bc + 1;
        bs = (bs == 2) ? 0 : bs + 1;
    }

#pragma unroll
    for (int ni = 0; ni < 4; ++ni) {
        const int gc = col0 + wn * 64 + ni * 16 + l15;
        const float bv = bias[gc];
        const int hh = gc / 192;
        const int rem = gc - hh * 192;
        const int which = rem >> 6, d = rem & 63;
#pragma unroll
        for (int mi = 0; mi < 4; ++mi)
#pragma unroll
            for (int i = 0; i < 4; ++i) {
                const int gr = row0 + wm * 64 + mi * 16 + quad * 4 + i;
                const int s = gr >> 2, bb = gr & 3;      // row = s*B + b
                float fv = acc[mi][ni][i] + bv;
                const size_t ho = (size_t)(bb * NH_ + hh);
                // 0.125 * log2(e): scores arrive pre-multiplied for exp2
                if (which == 0)      Qb[(ho * S_ + s) * HD_ + d] = f2bf(fv * 0.1803368801111204f);
                else if (which == 1) Kb[(ho * S_ + s) * HD_ + d] = f2bf(fv);
                else                 Vb[(ho * S_ + s) * HD_ + d] = f2bf(fv);
            }
    }
}

// ---------------------------------------------------------------------------
// V transpose: Vb [bh][s][d] -> Vtb [bh][d][s], 64x64 tiles via swizzled LDS.
// ---------------------------------------------------------------------------
__global__ __launch_bounds__(256) void vtrans_kernel(
    const short* __restrict__ Vb, short* __restrict__ Vtb)
{
    const int bh = blockIdx.y;
    const int s0 = blockIdx.x * 64;
    __shared__ __align__(16) short T[64 * 64];
    const int t = threadIdx.x;

#pragma unroll
    for (int it = 0; it < 2; ++it) {
        const int c = t + it * 256;
        const int r = c >> 3, jp = c & 7;
        const int jg = jp ^ ((r >> 3) & 7);
        *(short8*)&T[r * 64 + jp * 8] =
            *(const short8*)(Vb + ((size_t)bh * S_ + s0 + r) * HD_ + jg * 8);
    }
    __syncthreads();

#pragma unroll
    for (int it = 0; it < 2; ++it) {
        const int c = t + it * 256;
        const int d = c >> 3, sg = (c & 7) * 8;
        short8 v;
#pragma unroll
        for (int k = 0; k < 8; ++k) {
            const int r = sg + k;
            v[k] = T[r * 64 + (((d >> 3) ^ ((r >> 3) & 7)) * 8) + (d & 7)];
        }
        *(short8*)(Vtb + ((size_t)bh * HD_ + d) * S_ + s0 + sg) = v;
    }
}

// ---------------------------------------------------------------------------
// Dense GEMM v2: same BK=32 depth-2 counted-vmcnt pipeline as gemm_qkv.
// ---------------------------------------------------------------------------
__global__ __launch_bounds__(256, 3) void gemm_dense_mfma(
    const short* __restrict__ A, const short* __restrict__ Bw,
    const float* __restrict__ bias, float* __restrict__ out)
{
    constexpr int K = H_;  // 1024
    __shared__ __align__(16) short As[3 * 4096];
    __shared__ __align__(16) short Bs[3 * 4096];

    const int t = threadIdx.x;
    const int wave = t >> 6, lane = t & 63;
    const int l15 = lane & 15, quad = lane >> 4;
    const int wm = wave & 1, wn = wave >> 1;
    const int row0 = blockIdx.y * 128;
    const int col0 = blockIdx.x * 128;

    floatx4 acc[4][4];
#pragma unroll
    for (int mi = 0; mi < 4; ++mi)
#pragma unroll
        for (int ni = 0; ni < 4; ++ni)
            acc[mi][ni] = (floatx4){0.f, 0.f, 0.f, 0.f};

    const int c0 = wave * 128 + lane, c1 = c0 + 64;
    const int r0 = c0 >> 2, jg0 = (((c0 & 3) ^ (((r0 & 3) + ((r0 >> 2) & 3)) & 3))) * 8;
    const int r1 = c1 >> 2, jg1 = (((c1 & 3) ^ (((r1 & 3) + ((r1 >> 2) & 3)) & 3))) * 8;
    const int db0 = (wave * 128) * 8;
    const int db1 = db0 + 64 * 8;

    const short* Ar0 = A  + (size_t)(row0 + r0) * K + jg0;
    const short* Ar1 = A  + (size_t)(row0 + r1) * K + jg1;
    const short* Br0 = Bw + (size_t)(col0 + r0) * K + jg0;
    const short* Br1 = Bw + (size_t)(col0 + r1) * K + jg1;

    gl2lds16(Ar0, &As[db0]); gl2lds16(Ar1, &As[db1]);
    gl2lds16(Br0, &Bs[db0]); gl2lds16(Br1, &Bs[db1]);
    __builtin_amdgcn_sched_barrier(0);
    gl2lds16(Ar0 + 32, &As[4096 + db0]); gl2lds16(Ar1 + 32, &As[4096 + db1]);
    gl2lds16(Br0 + 32, &Bs[4096 + db0]); gl2lds16(Br1 + 32, &Bs[4096 + db1]);
    __builtin_amdgcn_sched_barrier(0);

    int bc = 0, bs = 2;
#pragma unroll 1
    for (int it = 0; it < 32; ++it) {
        if (it < 31) { asm volatile("s_waitcnt vmcnt(4)" ::: "memory"); }
        else         { asm volatile("s_waitcnt vmcnt(0)" ::: "memory"); }
        __builtin_amdgcn_s_barrier();
        __builtin_amdgcn_sched_barrier(0);

        if (it < 30) {
            const int ko = (it + 2) * 32;
            gl2lds16(Ar0 + ko, &As[bs * 4096 + db0]);
            gl2lds16(Ar1 + ko, &As[bs * 4096 + db1]);
            gl2lds16(Br0 + ko, &Bs[bs * 4096 + db0]);
            gl2lds16(Br1 + ko, &Bs[bs * 4096 + db1]);
        }
        __builtin_amdgcn_sched_barrier(0);

        const int bo = bc * 4096;
        short8 af[4], bfr[4];
#pragma unroll
        for (int mi = 0; mi < 4; ++mi) {
            const int R = wm * 64 + mi * 16 + l15;
            const int sel = quad ^ (((R & 3) + ((R >> 2) & 3)) & 3);
            af[mi] = *(const short8*)&As[bo + R * 32 + sel * 8];
        }
#pragma unroll
        for (int ni = 0; ni < 4; ++ni) {
            const int R = wn * 64 + ni * 16 + l15;
            const int sel = quad ^ (((R & 3) + ((R >> 2) & 3)) & 3);
            bfr[ni] = *(const short8*)&Bs[bo + R * 32 + sel * 8];
        }
        __builtin_amdgcn_s_setprio(1);
#pragma unroll
        for (int mi = 0; mi < 4; ++mi)
#pragma unroll
            for (int ni = 0; ni < 4; ++ni)
                acc[mi][ni] = __builtin_amdgcn_mfma_f32_16x16x32_bf16(
                    af[mi], bfr[ni], acc[mi][ni], 0, 0, 0);
        __builtin_amdgcn_s_setprio(0);

        bc = (bc == 2) ? 0 : bc + 1;
        bs = (bs == 2) ? 0 : bs + 1;
    }

#pragma unroll
    for (int ni = 0; ni < 4; ++ni) {
        const int gc = col0 + wn * 64 + ni * 16 + l15;
        const float bv = bias[gc];
#pragma unroll
        for (int mi = 0; mi < 4; ++mi)
#pragma unroll
            for (int i = 0; i < 4; ++i) {
                const int gr = row0 + wm * 64 + mi * 16 + quad * 4 + i;
                out[(size_t)gr * H_ + gc] = acc[mi][ni][i] + bv;
            }
    }
}

// ---------------------------------------------------------------------------
// Flash attention v8, MFMA bf16.
//   R7 analysis: 112us, VALU 45 + MFMA 29 = 74% of issue with only 2
//   waves/SIMD -> TLP-starved; 72KB LDS (24KB byte-masks) is the binding
//   constraint. v8:
//   * 8 waves / 512 threads, QBLK=256: each K/V/mask LDS byte feeds 2x the
//     MFMAs; K/V HBM demand per q halves. Per-wave register layout identical
//     to v7 (2 q-groups of 16).
//   * mask as BITS [b][tb][q] u64 (mask_bit_kernel): 2KB/buf instead of
//     16KB -> LDS = 3*(8+8+2)KB + 128B LUT ~ 54KB -> 2 blocks/CU =
//     16 waves/CU = 4 waves/SIMD (2x TLP).
//   * bit->{m0,m1} byte-mask expansion via 16-entry LDS LUT (conflict-free:
//     16 u64 entries span all 32 banks; same-nib lanes broadcast).
//   * ledger: 3 gl2lds/tile/wave (K16,V16,M4) -> vmcnt(3), depth-2, 3 bufs.
//     All loop VMEM is LDS-destined (R4/R5/R6 rule).
// ---------------------------------------------------------------------------
__global__ __launch_bounds__(512, 4) void flash_mfma_kernel(
    const short* __restrict__ Qb, const short* __restrict__ Kb,
    const short* __restrict__ Vtb, const unsigned long long* __restrict__ mbits,
    short* __restrict__ ctxb)
{
    const int bh = blockIdx.y;
    const int b  = bh >> 4;          // / NH_
    const int h  = bh & 15;          // % NH_
    const int s0 = blockIdx.x * 256;

    const int tdx  = threadIdx.x;
    const int wave = tdx >> 6;       // 0..7
    const int lane = tdx & 63;
    const int l15  = lane & 15;
    const int quad = lane >> 4;

    __shared__ __align__(16) short Ks [3 * 4096];   // [buf][key64][d64]
    __shared__ __align__(16) short Vts[3 * 4096];   // [buf][d64][key64]
    __shared__ __align__(16) uint2v Mb[3 * 256];    // [buf][q256] bit-rows (u64)
    __shared__ __align__(16) uint2v Mlut[16];       // nib -> {m0, m1}

    // LUT init (before any staging; __syncthreads here is pre-pipeline)
    if (tdx < 16) {
        const unsigned m0 = ((tdx & 1) ? 0xFFFFu : 0u) | ((tdx & 2) ? 0xFFFF0000u : 0u);
        const unsigned m1 = ((tdx & 4) ? 0xFFFFu : 0u) | ((tdx & 8) ? 0xFFFF0000u : 0u);
        Mlut[tdx] = (uint2v){m0, m1};
    }
    __syncthreads();

    // Q fragments: wave owns q rows [s0+wave*32, +32), 2 groups of 16
    const short* Qg = Qb + ((size_t)bh * S_ + s0 + wave * 32 + l15) * HD_;
    short8 qf00 = *(const short8*)(Qg + quad * 8);
    short8 qf01 = *(const short8*)(Qg + 32 + quad * 8);
    short8 qf10 = *(const short8*)(Qg + 16 * HD_ + quad * 8);
    short8 qf11 = *(const short8*)(Qg + 16 * HD_ + 32 + quad * 8);

    const short* Kbase  = Kb  + (size_t)bh * S_ * HD_;
    const short* Vtbase = Vtb + (size_t)bh * HD_ * S_;

    floatx4 o[2][4];
    floatx4 lacc[2];
#pragma unroll
    for (int g = 0; g < 2; ++g) {
        lacc[g] = (floatx4){0.f, 0.f, 0.f, 0.f};
#pragma unroll
        for (int n0 = 0; n0 < 4; ++n0) o[g][n0] = (floatx4){0.f, 0.f, 0.f, 0.f};
    }
    const short8 ones8 = {(short)0x3F80, (short)0x3F80, (short)0x3F80, (short)0x3F80,
                          (short)0x3F80, (short)0x3F80, (short)0x3F80, (short)0x3F80};

    // K/V staging geometry: 512 chunks/tile, 64 per wave
    const int c0 = wave * 64 + lane;
    const int r0 = c0 >> 3, jg0 = ((c0 & 7) ^ (r0 & 7)) * 8;
    const int kvdst = wave * 512;                     // + buf*4096 (elems)
    // M staging: wave stages its 32 rows (256 B) linearly, 4 B/lane
    const char* msrc = (const char*)mbits + ((size_t)(b * 32) * 2048 + s0 + wave * 32) * 8 + lane * 4;
    const int   mdst = wave * 256;                    // bytes; + buf*2048

    // prologue: stage(0) -> buf0, stage(1) -> buf1 (FIFO blocks of 3)
    gl2lds16(Kbase  + (size_t)r0 * HD_ + jg0, &Ks[kvdst]);
    gl2lds16(Vtbase + (size_t)r0 * S_ + jg0,  &Vts[kvdst]);
    gl2lds4 (msrc,                            (char*)Mb + mdst);
    __builtin_amdgcn_sched_barrier(0);
    gl2lds16(Kbase  + (size_t)(64 + r0) * HD_ + jg0, &Ks[4096 + kvdst]);
    gl2lds16(Vtbase + (size_t)r0 * S_ + 64 + jg0,    &Vts[4096 + kvdst]);
    gl2lds4 (msrc + 2048 * 8,                        (char*)Mb + 2048 + mdst);
    __builtin_amdgcn_sched_barrier(0);

    const floatx4 z4 = {0.f, 0.f, 0.f, 0.f};
    const int qsh = quad * 4;
    int bc = 0, bs = 2;   // compute / stage buffer indices

#pragma unroll 1
    for (int it = 0; it < 32; ++it) {
        // counted wait: stage(it) retired; stage(it+1) [3 ops] may remain
        if (it < 31) { asm volatile("s_waitcnt vmcnt(3)" ::: "memory"); }
        else         { asm volatile("s_waitcnt vmcnt(0)" ::: "memory"); }
        __builtin_amdgcn_s_barrier();
        __builtin_amdgcn_sched_barrier(0);

        // stage tile it+2 into buf bs (FIFO block of 3)
        if (it < 30) {
            const size_t tn = (size_t)(it + 2) * 64;
            gl2lds16(Kbase  + (tn + r0) * HD_ + jg0,      &Ks[bs * 4096 + kvdst]);
            gl2lds16(Vtbase + (size_t)r0 * S_ + tn + jg0, &Vts[bs * 4096 + kvdst]);
            gl2lds4 (msrc + (size_t)(it + 2) * 2048 * 8,  (char*)Mb + bs * 2048 + mdst);
        }
        __builtin_amdgcn_sched_barrier(0);

        // ---- compute tile it from buf bc ----
        const int bo = bc * 4096;
        floatx4 sc[2][4];
        __builtin_amdgcn_s_setprio(1);
#pragma unroll
        for (int n0 = 0; n0 < 4; ++n0) {
            const int R = n0 * 16 + l15, xr = R & 7;
            const short8 kb0 = *(const short8*)&Ks[bo + R * 64 + ((quad ^ xr) * 8)];
            const short8 kb1 = *(const short8*)&Ks[bo + R * 64 + (((quad + 4) ^ xr) * 8)];
            sc[0][n0] = __builtin_amdgcn_mfma_f32_16x16x32_bf16(kb0, qf00, z4, 0, 0, 0);
            sc[0][n0] = __builtin_amdgcn_mfma_f32_16x16x32_bf16(kb1, qf01, sc[0][n0], 0, 0, 0);
            sc[1][n0] = __builtin_amdgcn_mfma_f32_16x16x32_bf16(kb0, qf10, z4, 0, 0, 0);
            sc[1][n0] = __builtin_amdgcn_mfma_f32_16x16x32_bf16(kb1, qf11, sc[1][n0], 0, 0, 0);
        }
        __builtin_amdgcn_s_setprio(0);

        // row bit-words for both groups (one ds_read_b64 each; quads broadcast)
        const uint2v row0b = Mb[bc * 256 + wave * 32 + l15];
        const uint2v row1b = Mb[bc * 256 + wave * 32 + 16 + l15];

        unsigned uu[2][4][2];
#pragma unroll
        for (int g = 0; g < 2; ++g) {
            const uint2v rw = g ? row1b : row0b;
#pragma unroll
            for (int n0 = 0; n0 < 4; ++n0) {
                const unsigned selw = (n0 < 2) ? rw.x : rw.y;
                const unsigned nib = (selw >> (qsh + ((n0 & 1) << 4))) & 15u;
                const uint2v mm = Mlut[nib];
                const floatx4 v = sc[g][n0];
                const unsigned u0 = pack_bf(__builtin_amdgcn_exp2f(v[0]),
                                            __builtin_amdgcn_exp2f(v[1])) & mm.x;
                const unsigned u1 = pack_bf(__builtin_amdgcn_exp2f(v[2]),
                                            __builtin_amdgcn_exp2f(v[3])) & mm.y;
                uu[g][n0][0] = u0; uu[g][n0][1] = u1;
            }
        }
        short8 pa00 = pswz(uu[0][0][0], uu[0][0][1], uu[0][1][0], uu[0][1][1]);
        short8 pa01 = pswz(uu[0][2][0], uu[0][2][1], uu[0][3][0], uu[0][3][1]);
        short8 pa10 = pswz(uu[1][0][0], uu[1][0][1], uu[1][1][0], uu[1][1][1]);
        short8 pa11 = pswz(uu[1][2][0], uu[1][2][1], uu[1][3][0], uu[1][3][1]);

        __builtin_amdgcn_s_setprio(1);
        // l accumulation via all-ones B operand (no VALU chain, no shuffles)
        lacc[0] = __builtin_amdgcn_mfma_f32_16x16x32_bf16(pa00, ones8, lacc[0], 0, 0, 0);
        lacc[0] = __builtin_amdgcn_mfma_f32_16x16x32_bf16(pa01, ones8, lacc[0], 0, 0, 0);
        lacc[1] = __builtin_amdgcn_mfma_f32_16x16x32_bf16(pa10, ones8, lacc[1], 0, 0, 0);
        lacc[1] = __builtin_amdgcn_mfma_f32_16x16x32_bf16(pa11, ones8, lacc[1], 0, 0, 0);
#pragma unroll
        for (int n0 = 0; n0 < 4; ++n0) {
            const int R = n0 * 16 + l15, xr = R & 7;
            const short8 vb0 = *(const short8*)&Vts[bo + R * 64 + ((quad ^ xr) * 8)];
            const short8 vb1 = *(const short8*)&Vts[bo + R * 64 + (((quad + 4) ^ xr) * 8)];
            o[0][n0] = __builtin_amdgcn_mfma_f32_16x16x32_bf16(pa00, vb0, o[0][n0], 0, 0, 0);
            o[0][n0] = __builtin_amdgcn_mfma_f32_16x16x32_bf16(pa01, vb1, o[0][n0], 0, 0, 0);
            o[1][n0] = __builtin_amdgcn_mfma_f32_16x16x32_bf16(pa10, vb0, o[1][n0], 0, 0, 0);
            o[1][n0] = __builtin_amdgcn_mfma_f32_16x16x32_bf16(pa11, vb1, o[1][n0], 0, 0, 0);
        }
        __builtin_amdgcn_s_setprio(0);

        bc = (bc == 2) ? 0 : bc + 1;
        bs = (bs == 2) ? 0 : bs + 1;
    }

    // --- epilogue: lacc[g][i] = l[q = g*16 + quad*4 + i] in-lane ---
#pragma unroll
    for (int g = 0; g < 2; ++g) {
#pragma unroll
        for (int i = 0; i < 4; ++i) {
            const float la = 1.f / lacc[g][i];
            const int sA = s0 + wave * 32 + g * 16 + quad * 4 + i;
#pragma unroll
            for (int n0 = 0; n0 < 4; ++n0)
                ctxb[((size_t)sA * B_ + b) * H_ + h * HD_ + n0 * 16 + l15] =
                    f2bf(o[g][n0][i] * la);
        }
    }
}

// ---------------------------------------------------------------------------
extern "C" void kernel_launch(void* const* d_in, const int* in_sizes, int n_in,
                              void* d_out, int out_size, void* d_ws, size_t ws_size,
                              hipStream_t stream)
{
    const float* hidden = (const float*)d_in[0];
    const int*   mask   = (const int*)d_in[1];
    const float* Wqkv   = (const float*)d_in[2];
    const float* bqkv   = (const float*)d_in[3];
    const float* Wd     = (const float*)d_in[4];
    const float* bd     = (const float*)d_in[5];
    float* out = (float*)d_out;

    const size_t HE = (size_t)B_ * NH_ * S_ * HD_;   // 8388608
    short* hBF    = (short*)d_ws;
    short* WqkvBF = hBF + (size_t)S_ * B_ * H_;
    short* WdBF   = WqkvBF + (size_t)3 * H_ * H_;
    short* Qb     = WdBF + (size_t)H_ * H_;
    short* Kb     = Qb + HE;
    short* Vb     = Kb + HE;
    short* Vtb    = Vb + HE;
    short* ctxb   = Vtb + HE;
    // mask bit-words: B*32*2048*8 B = 2 MB -> alias hBF (dead after gemm_qkv;
    // mask_bit launched after it, stream-ordered).
    unsigned long long* mbits = (unsigned long long*)hBF;

    const int nh4 = (S_ * B_ * H_) / 4;   // 2097152
    const int nw4 = (3 * H_ * H_) / 4;    // 786432
    const int nd4 = (H_ * H_) / 4;        // 262144
    hipLaunchKernelGGL(cvt3_kernel, dim3((nh4 + nw4 + nd4) / 256), dim3(256), 0, stream,
                       hidden, hBF, nh4, Wqkv, WqkvBF, nw4, Wd, WdBF, nd4);

    hipLaunchKernelGGL(gemm_qkv_mfma, dim3((3 * H_) / 128, (S_ * B_) / 128), dim3(256), 0, stream,
                       hBF, WqkvBF, bqkv, Qb, Kb, Vb);
    hipLaunchKernelGGL(mask_bit_kernel, dim3(B_ * S_ * 32 / 4), dim3(256), 0, stream,
                       mask, mbits);
    hipLaunchKernelGGL(vtrans_kernel, dim3(S_ / 64, B_ * NH_), dim3(256), 0, stream,
                       Vb, Vtb);
    hipLaunchKernelGGL(flash_mfma_kernel, dim3(S_ / 256, B_ * NH_), dim3(512), 0, stream,
                       Qb, Kb, Vtb, mbits, ctxb);
    hipLaunchKernelGGL(gemm_dense_mfma, dim3(H_ / 128, (S_ * B_) / 128), dim3(256), 0, stream,
                       ctxb, WdBF, bd, out);
}

// Round 10
// 338.026 us; speedup vs baseline: 1.0681x; 1.0681x over previous
//
#include <hip/hip_runtime.h>
#include <hip/hip_bf16.h>
#include <math.h>

// S,B,H,NH = 2048,4,1024,16; HD=64
constexpr int S_ = 2048, B_ = 4, H_ = 1024, NH_ = 16, HD_ = 64;

typedef __attribute__((ext_vector_type(8))) short short8;   // 8 bf16 (4 VGPRs)
typedef __attribute__((ext_vector_type(4))) short short4v;  // 4 bf16
typedef __attribute__((ext_vector_type(4))) float floatx4;  // MFMA C/D
typedef __attribute__((ext_vector_type(2))) unsigned uint2v;

static __device__ __forceinline__ short f2bf(float f) {
    union { float f; unsigned u; } v; v.f = f;
    unsigned r = v.u + 0x7FFFu + ((v.u >> 16) & 1u);  // RNE
    return (short)(r >> 16);
}

// pack two f32 -> one u32 of two bf16 (truncation), via v_perm_b32
static __device__ __forceinline__ unsigned pack_bf(float p0, float p1) {
    return __builtin_amdgcn_perm(__float_as_uint(p1), __float_as_uint(p0), 0x07060302u);
}

// async global->LDS; LDS dest = wave-uniform base + lane*size
static __device__ __forceinline__ void gl2lds16(const void* g, void* l) {
    __builtin_amdgcn_global_load_lds(
        (const __attribute__((address_space(1))) void*)g,
        (__attribute__((address_space(3))) void*)l, 16, 0, 0);
}
static __device__ __forceinline__ void gl2lds4(const void* g, void* l) {
    __builtin_amdgcn_global_load_lds(
        (const __attribute__((address_space(1))) void*)g,
        (__attribute__((address_space(3))) void*)l, 4, 0, 0);
}

// P-fragment redistribution (in-register, replaces Ps LDS round-trip).
static __device__ __forceinline__ short8 pswz(unsigned a0, unsigned a1,
                                              unsigned b0, unsigned b1) {
    uint2v r0 = __builtin_amdgcn_permlane32_swap(a0, b0, false, false);
    uint2v s0 = __builtin_amdgcn_permlane16_swap(r0.x, r0.y, false, false);
    uint2v r1 = __builtin_amdgcn_permlane32_swap(a1, b1, false, false);
    uint2v s1 = __builtin_amdgcn_permlane16_swap(r1.x, r1.y, false, false);
    union { unsigned u[4]; short8 s; } o;
    o.u[0] = s0.x;  // W0: t = dq*8 + {0,1}
    o.u[1] = s1.x;  // W1: t = dq*8 + {2,3}
    o.u[2] = s0.y;  // W2: t = dq*8 + {4,5}
    o.u[3] = s1.y;  // W3: t = dq*8 + {6,7}
    return o.s;
}

// spread 16 bits to every 4th bit position of a u64
static __device__ __forceinline__ unsigned long long spread4(unsigned x) {
    unsigned long long s = x;
    s = (s | (s << 24)) & 0x000000FF000000FFull;
    s = (s | (s << 12)) & 0x000F000F000F000Full;
    s = (s | (s << 6))  & 0x0303030303030303ull;
    s = (s | (s << 3))  & 0x1111111111111111ull;
    return s;
}

// ---------------------------------------------------------------------------
// fused fp32 -> bf16 convert for hidden / Wqkv / Wd
// ---------------------------------------------------------------------------
__global__ __launch_bounds__(256) void cvt3_kernel(
    const float* __restrict__ a, short* __restrict__ oa, int na,
    const float* __restrict__ b, short* __restrict__ ob, int nb,
    const float* __restrict__ c, short* __restrict__ oc, int nc)
{
    const int idx = blockIdx.x * 256 + threadIdx.x;
    const float* src; short* dst; int i;
    if (idx < na)            { src = a; dst = oa; i = idx; }
    else if (idx < na + nb)  { src = b; dst = ob; i = idx - na; }
    else                     { src = c; dst = oc; i = idx - na - nb; }
    const float4 v = ((const float4*)src)[i];
    short4v o = { (short)f2bf(v.x), (short)f2bf(v.y), (short)f2bf(v.z), (short)f2bf(v.w) };
    ((short4v*)dst)[i] = o;
}

// ---------------------------------------------------------------------------
// mask int32 -> keep-BITS, layout [b][tblk=32][q=2048] u64 (bit j of word =
// keep for t = tblk*64 + j).
// v2 (R9 fix): int4 per lane (coalesced 16B) -- R9's scalar-load version was
// latency-bound (+22us). Wave covers 256 t of one q row; 4 ballots + bit
// interleave assemble the 4 u64 words; lanes 0..3 store them.
// ---------------------------------------------------------------------------
__global__ __launch_bounds__(256) void mask_bit_kernel(
    const int* __restrict__ m, unsigned long long* __restrict__ mb)
{
    const int wid  = blockIdx.x * 4 + (threadIdx.x >> 6);
    const int lane = threadIdx.x & 63;
    const int b   = wid >> 14;           // 2048 q * 8 seg = 16384 per b
    const int rem = wid & 16383;
    const int q   = rem >> 3;
    const int seg = rem & 7;
    const int4 v = *(const int4*)(m + ((size_t)b * S_ + q) * S_ + seg * 256 + lane * 4);
    const unsigned nib = (v.x ? 0u : 1u) | (v.y ? 0u : 2u) |
                         (v.z ? 0u : 4u) | (v.w ? 0u : 8u);
    const unsigned long long b0 = __ballot((nib & 1u) != 0u);
    const unsigned long long b1 = __ballot((nib & 2u) != 0u);
    const unsigned long long b2 = __ballot((nib & 4u) != 0u);
    const unsigned long long b3 = __ballot((nib & 8u) != 0u);
    if (lane < 4) {
        const int sh = lane * 16;
        const unsigned long long w =
            spread4((unsigned)((b0 >> sh) & 0xFFFFu)) |
            (spread4((unsigned)((b1 >> sh) & 0xFFFFu)) << 1) |
            (spread4((unsigned)((b2 >> sh) & 0xFFFFu)) << 2) |
            (spread4((unsigned)((b3 >> sh) & 0xFFFFu)) << 3);
        mb[((size_t)b * 32 + seg * 4 + lane) * 2048 + q] = w;
    }
}

// ---------------------------------------------------------------------------
// QKV GEMM v3: BK=32, 3 LDS buffers, depth-2 counted-vmcnt pipeline +
// bijective XCD swizzle (each XCD owns 8 row-panels; x slowest within chunk
// -> B-panel reuse distance 1, A working set 2MB L2-fits).
// ---------------------------------------------------------------------------
__global__ __launch_bounds__(256, 3) void gemm_qkv_mfma(
    const short* __restrict__ A, const short* __restrict__ Bw,
    const float* __restrict__ bias,
    short* __restrict__ Qb, short* __restrict__ Kb, short* __restrict__ Vb)
{
    constexpr int K = H_;  // 1024
    __shared__ __align__(16) short As[3 * 4096];
    __shared__ __align__(16) short Bs[3 * 4096];

    const int t = threadIdx.x;
    const int wave = t >> 6, lane = t & 63;
    const int l15 = lane & 15, quad = lane >> 4;
    const int wm = wave & 1, wn = wave >> 1;
    // XCD swizzle: grid (24,64) = 1536 blocks, 192/XCD = 8 row-panels x 24 cols
    const int L  = blockIdx.y * 24 + blockIdx.x;
    const int n  = L >> 3;
    const int row0 = (((L & 7) << 3) + (n & 7)) * 128;
    const int col0 = (n >> 3) * 128;

    floatx4 acc[4][4];
#pragma unroll
    for (int mi = 0; mi < 4; ++mi)
#pragma unroll
        for (int ni = 0; ni < 4; ++ni)
            acc[mi][ni] = (floatx4){0.f, 0.f, 0.f, 0.f};

    const int c0 = wave * 128 + lane, c1 = c0 + 64;
    const int r0 = c0 >> 2, jg0 = (((c0 & 3) ^ (((r0 & 3) + ((r0 >> 2) & 3)) & 3))) * 8;
    const int r1 = c1 >> 2, jg1 = (((c1 & 3) ^ (((r1 & 3) + ((r1 >> 2) & 3)) & 3))) * 8;
    const int db0 = (wave * 128) * 8;
    const int db1 = db0 + 64 * 8;

    const short* Ar0 = A  + (size_t)(row0 + r0) * K + jg0;
    const short* Ar1 = A  + (size_t)(row0 + r1) * K + jg1;
    const short* Br0 = Bw + (size_t)(col0 + r0) * K + jg0;
    const short* Br1 = Bw + (size_t)(col0 + r1) * K + jg1;

    gl2lds16(Ar0, &As[db0]); gl2lds16(Ar1, &As[db1]);
    gl2lds16(Br0, &Bs[db0]); gl2lds16(Br1, &Bs[db1]);
    __builtin_amdgcn_sched_barrier(0);
    gl2lds16(Ar0 + 32, &As[4096 + db0]); gl2lds16(Ar1 + 32, &As[4096 + db1]);
    gl2lds16(Br0 + 32, &Bs[4096 + db0]); gl2lds16(Br1 + 32, &Bs[4096 + db1]);
    __builtin_amdgcn_sched_barrier(0);

    int bc = 0, bs = 2;
#pragma unroll 1
    for (int it = 0; it < 32; ++it) {
        if (it < 31) { asm volatile("s_waitcnt vmcnt(4)" ::: "memory"); }
        else         { asm volatile("s_waitcnt vmcnt(0)" ::: "memory"); }
        __builtin_amdgcn_s_barrier();
        __builtin_amdgcn_sched_barrier(0);

        if (it < 30) {
            const int ko = (it + 2) * 32;
            gl2lds16(Ar0 + ko, &As[bs * 4096 + db0]);
            gl2lds16(Ar1 + ko, &As[bs * 4096 + db1]);
            gl2lds16(Br0 + ko, &Bs[bs * 4096 + db0]);
            gl2lds16(Br1 + ko, &Bs[bs * 4096 + db1]);
        }
        __builtin_amdgcn_sched_barrier(0);

        const int bo = bc * 4096;
        short8 af[4], bfr[4];
#pragma unroll
        for (int mi = 0; mi < 4; ++mi) {
            const int R = wm * 64 + mi * 16 + l15;
            const int sel = quad ^ (((R & 3) + ((R >> 2) & 3)) & 3);
            af[mi] = *(const short8*)&As[bo + R * 32 + sel * 8];
        }
#pragma unroll
        for (int ni = 0; ni < 4; ++ni) {
            const int R = wn * 64 + ni * 16 + l15;
            const int sel = quad ^ (((R & 3) + ((R >> 2) & 3)) & 3);
            bfr[ni] = *(const short8*)&Bs[bo + R * 32 + sel * 8];
        }
        __builtin_amdgcn_s_setprio(1);
#pragma unroll
        for (int mi = 0; mi < 4; ++mi)
#pragma unroll
            for (int ni = 0; ni < 4; ++ni)
                acc[mi][ni] = __builtin_amdgcn_mfma_f32_16x16x32_bf16(
                    af[mi], bfr[ni], acc[mi][ni], 0, 0, 0);
        __builtin_amdgcn_s_setprio(0);

        bc = (bc == 2) ? 0 : bc + 1;
        bs = (bs == 2) ? 0 : bs + 1;
    }

#pragma unroll
    for (int ni = 0; ni < 4; ++ni) {
        const int gc = col0 + wn * 64 + ni * 16 + l15;
        const float bv = bias[gc];
        const int hh = gc / 192;
        const int rem = gc - hh * 192;
        const int which = rem >> 6, d = rem & 63;
#pragma unroll
        for (int mi = 0; mi < 4; ++mi)
#pragma unroll
            for (int i = 0; i < 4; ++i) {
                const int gr = row0 + wm * 64 + mi * 16 + quad * 4 + i;
                const int s = gr >> 2, bb = gr & 3;      // row = s*B + b
                float fv = acc[mi][ni][i] + bv;
                const size_t ho = (size_t)(bb * NH_ + hh);
                // 0.125 * log2(e): scores arrive pre-multiplied for exp2
                if (which == 0)      Qb[(ho * S_ + s) * HD_ + d] = f2bf(fv * 0.1803368801111204f);
                else if (which == 1) Kb[(ho * S_ + s) * HD_ + d] = f2bf(fv);
                else                 Vb[(ho * S_ + s) * HD_ + d] = f2bf(fv);
            }
    }
}

// ---------------------------------------------------------------------------
// V transpose: Vb [bh][s][d] -> Vtb [bh][d][s], 64x64 tiles via swizzled LDS.
// ---------------------------------------------------------------------------
__global__ __launch_bounds__(256) void vtrans_kernel(
    const short* __restrict__ Vb, short* __restrict__ Vtb)
{
    const int bh = blockIdx.y;
    const int s0 = blockIdx.x * 64;
    __shared__ __align__(16) short T[64 * 64];
    const int t = threadIdx.x;

#pragma unroll
    for (int it = 0; it < 2; ++it) {
        const int c = t + it * 256;
        const int r = c >> 3, jp = c & 7;
        const int jg = jp ^ ((r >> 3) & 7);
        *(short8*)&T[r * 64 + jp * 8] =
            *(const short8*)(Vb + ((size_t)bh * S_ + s0 + r) * HD_ + jg * 8);
    }
    __syncthreads();

#pragma unroll
    for (int it = 0; it < 2; ++it) {
        const int c = t + it * 256;
        const int d = c >> 3, sg = (c & 7) * 8;
        short8 v;
#pragma unroll
        for (int k = 0; k < 8; ++k) {
            const int r = sg + k;
            v[k] = T[r * 64 + (((d >> 3) ^ ((r >> 3) & 7)) * 8) + (d & 7)];
        }
        *(short8*)(Vtb + ((size_t)bh * HD_ + d) * S_ + s0 + sg) = v;
    }
}

// ---------------------------------------------------------------------------
// Dense GEMM v3: BK=32 depth-2 counted-vmcnt pipeline + XCD swizzle.
// ---------------------------------------------------------------------------
__global__ __launch_bounds__(256, 3) void gemm_dense_mfma(
    const short* __restrict__ A, const short* __restrict__ Bw,
    const float* __restrict__ bias, float* __restrict__ out)
{
    constexpr int K = H_;  // 1024
    __shared__ __align__(16) short As[3 * 4096];
    __shared__ __align__(16) short Bs[3 * 4096];

    const int t = threadIdx.x;
    const int wave = t >> 6, lane = t & 63;
    const int l15 = lane & 15, quad = lane >> 4;
    const int wm = wave & 1, wn = wave >> 1;
    // XCD swizzle: grid (8,64) = 512 blocks, 64/XCD = 8 row-panels x 8 cols
    const int L  = blockIdx.y * 8 + blockIdx.x;
    const int n  = L >> 3;
    const int row0 = (((L & 7) << 3) + (n & 7)) * 128;
    const int col0 = (n >> 3) * 128;

    floatx4 acc[4][4];
#pragma unroll
    for (int mi = 0; mi < 4; ++mi)
#pragma unroll
        for (int ni = 0; ni < 4; ++ni)
            acc[mi][ni] = (floatx4){0.f, 0.f, 0.f, 0.f};

    const int c0 = wave * 128 + lane, c1 = c0 + 64;
    const int r0 = c0 >> 2, jg0 = (((c0 & 3) ^ (((r0 & 3) + ((r0 >> 2) & 3)) & 3))) * 8;
    const int r1 = c1 >> 2, jg1 = (((c1 & 3) ^ (((r1 & 3) + ((r1 >> 2) & 3)) & 3))) * 8;
    const int db0 = (wave * 128) * 8;
    const int db1 = db0 + 64 * 8;

    const short* Ar0 = A  + (size_t)(row0 + r0) * K + jg0;
    const short* Ar1 = A  + (size_t)(row0 + r1) * K + jg1;
    const short* Br0 = Bw + (size_t)(col0 + r0) * K + jg0;
    const short* Br1 = Bw + (size_t)(col0 + r1) * K + jg1;

    gl2lds16(Ar0, &As[db0]); gl2lds16(Ar1, &As[db1]);
    gl2lds16(Br0, &Bs[db0]); gl2lds16(Br1, &Bs[db1]);
    __builtin_amdgcn_sched_barrier(0);
    gl2lds16(Ar0 + 32, &As[4096 + db0]); gl2lds16(Ar1 + 32, &As[4096 + db1]);
    gl2lds16(Br0 + 32, &Bs[4096 + db0]); gl2lds16(Br1 + 32, &Bs[4096 + db1]);
    __builtin_amdgcn_sched_barrier(0);

    int bc = 0, bs = 2;
#pragma unroll 1
    for (int it = 0; it < 32; ++it) {
        if (it < 31) { asm volatile("s_waitcnt vmcnt(4)" ::: "memory"); }
        else         { asm volatile("s_waitcnt vmcnt(0)" ::: "memory"); }
        __builtin_amdgcn_s_barrier();
        __builtin_amdgcn_sched_barrier(0);

        if (it < 30) {
            const int ko = (it + 2) * 32;
            gl2lds16(Ar0 + ko, &As[bs * 4096 + db0]);
            gl2lds16(Ar1 + ko, &As[bs * 4096 + db1]);
            gl2lds16(Br0 + ko, &Bs[bs * 4096 + db0]);
            gl2lds16(Br1 + ko, &Bs[bs * 4096 + db1]);
        }
        __builtin_amdgcn_sched_barrier(0);

        const int bo = bc * 4096;
        short8 af[4], bfr[4];
#pragma unroll
        for (int mi = 0; mi < 4; ++mi) {
            const int R = wm * 64 + mi * 16 + l15;
            const int sel = quad ^ (((R & 3) + ((R >> 2) & 3)) & 3);
            af[mi] = *(const short8*)&As[bo + R * 32 + sel * 8];
        }
#pragma unroll
        for (int ni = 0; ni < 4; ++ni) {
            const int R = wn * 64 + ni * 16 + l15;
            const int sel = quad ^ (((R & 3) + ((R >> 2) & 3)) & 3);
            bfr[ni] = *(const short8*)&Bs[bo + R * 32 + sel * 8];
        }
        __builtin_amdgcn_s_setprio(1);
#pragma unroll
        for (int mi = 0; mi < 4; ++mi)
#pragma unroll
            for (int ni = 0; ni < 4; ++ni)
                acc[mi][ni] = __builtin_amdgcn_mfma_f32_16x16x32_bf16(
                    af[mi], bfr[ni], acc[mi][ni], 0, 0, 0);
        __builtin_amdgcn_s_setprio(0);

        bc = (bc == 2) ? 0 : bc + 1;
        bs = (bs == 2) ? 0 : bs + 1;
    }

#pragma unroll
    for (int ni = 0; ni < 4; ++ni) {
        const int gc = col0 + wn * 64 + ni * 16 + l15;
        const float bv = bias[gc];
#pragma unroll
        for (int mi = 0; mi < 4; ++mi)
#pragma unroll
            for (int i = 0; i < 4; ++i) {
                const int gr = row0 + wm * 64 + mi * 16 + quad * 4 + i;
                out[(size_t)gr * H_ + gc] = acc[mi][ni][i] + bv;
            }
    }
}

// ---------------------------------------------------------------------------
// Flash attention v8 (unchanged from R9 -- verified 90.4us, VGPR 64, no
// spill, MfmaUtil 35/VALU 50 at 4 waves/SIMD: issue-bound).
// ---------------------------------------------------------------------------
__global__ __launch_bounds__(512, 4) void flash_mfma_kernel(
    const short* __restrict__ Qb, const short* __restrict__ Kb,
    const short* __restrict__ Vtb, const unsigned long long* __restrict__ mbits,
    short* __restrict__ ctxb)
{
    const int bh = blockIdx.y;
    const int b  = bh >> 4;          // / NH_
    const int h  = bh & 15;          // % NH_
    const int s0 = blockIdx.x * 256;

    const int tdx  = threadIdx.x;
    const int wave = tdx >> 6;       // 0..7
    const int lane = tdx & 63;
    const int l15  = lane & 15;
    const int quad = lane >> 4;

    __shared__ __align__(16) short Ks [3 * 4096];   // [buf][key64][d64]
    __shared__ __align__(16) short Vts[3 * 4096];   // [buf][d64][key64]
    __shared__ __align__(16) uint2v Mb[3 * 256];    // [buf][q256] bit-rows (u64)
    __shared__ __align__(16) uint2v Mlut[16];       // nib -> {m0, m1}

    // LUT init (before any staging; __syncthreads here is pre-pipeline)
    if (tdx < 16) {
        const unsigned m0 = ((tdx & 1) ? 0xFFFFu : 0u) | ((tdx & 2) ? 0xFFFF0000u : 0u);
        const unsigned m1 = ((tdx & 4) ? 0xFFFFu : 0u) | ((tdx & 8) ? 0xFFFF0000u : 0u);
        Mlut[tdx] = (uint2v){m0, m1};
    }
    __syncthreads();

    // Q fragments: wave owns q rows [s0+wave*32, +32), 2 groups of 16
    const short* Qg = Qb + ((size_t)bh * S_ + s0 + wave * 32 + l15) * HD_;
    short8 qf00 = *(const short8*)(Qg + quad * 8);
    short8 qf01 = *(const short8*)(Qg + 32 + quad * 8);
    short8 qf10 = *(const short8*)(Qg + 16 * HD_ + quad * 8);
    short8 qf11 = *(const short8*)(Qg + 16 * HD_ + 32 + quad * 8);

    const short* Kbase  = Kb  + (size_t)bh * S_ * HD_;
    const short* Vtbase = Vtb + (size_t)bh * HD_ * S_;

    floatx4 o[2][4];
    floatx4 lacc[2];
#pragma unroll
    for (int g = 0; g < 2; ++g) {
        lacc[g] = (floatx4){0.f, 0.f, 0.f, 0.f};
#pragma unroll
        for (int n0 = 0; n0 < 4; ++n0) o[g][n0] = (floatx4){0.f, 0.f, 0.f, 0.f};
    }
    const short8 ones8 = {(short)0x3F80, (short)0x3F80, (short)0x3F80, (short)0x3F80,
                          (short)0x3F80, (short)0x3F80, (short)0x3F80, (short)0x3F80};

    // K/V staging geometry: 512 chunks/tile, 64 per wave
    const int c0 = wave * 64 + lane;
    const int r0 = c0 >> 3, jg0 = ((c0 & 7) ^ (r0 & 7)) * 8;
    const int kvdst = wave * 512;                     // + buf*4096 (elems)
    // M staging: wave stages its 32 rows (256 B) linearly, 4 B/lane
    const char* msrc = (const char*)mbits + ((size_t)(b * 32) * 2048 + s0 + wave * 32) * 8 + lane * 4;
    const int   mdst = wave * 256;                    // bytes; + buf*2048

    // prologue: stage(0) -> buf0, stage(1) -> buf1 (FIFO blocks of 3)
    gl2lds16(Kbase  + (size_t)r0 * HD_ + jg0, &Ks[kvdst]);
    gl2lds16(Vtbase + (size_t)r0 * S_ + jg0,  &Vts[kvdst]);
    gl2lds4 (msrc,                            (char*)Mb + mdst);
    __builtin_amdgcn_sched_barrier(0);
    gl2lds16(Kbase  + (size_t)(64 + r0) * HD_ + jg0, &Ks[4096 + kvdst]);
    gl2lds16(Vtbase + (size_t)r0 * S_ + 64 + jg0,    &Vts[4096 + kvdst]);
    gl2lds4 (msrc + 2048 * 8,                        (char*)Mb + 2048 + mdst);
    __builtin_amdgcn_sched_barrier(0);

    const floatx4 z4 = {0.f, 0.f, 0.f, 0.f};
    const int qsh = quad * 4;
    int bc = 0, bs = 2;   // compute / stage buffer indices

#pragma unroll 1
    for (int it = 0; it < 32; ++it) {
        // counted wait: stage(it) retired; stage(it+1) [3 ops] may remain
        if (it < 31) { asm volatile("s_waitcnt vmcnt(3)" ::: "memory"); }
        else         { asm volatile("s_waitcnt vmcnt(0)" ::: "memory"); }
        __builtin_amdgcn_s_barrier();
        __builtin_amdgcn_sched_barrier(0);

        // stage tile it+2 into buf bs (FIFO block of 3)
        if (it < 30) {
            const size_t tn = (size_t)(it + 2) * 64;
            gl2lds16(Kbase  + (tn + r0) * HD_ + jg0,      &Ks[bs * 4096 + kvdst]);
            gl2lds16(Vtbase + (size_t)r0 * S_ + tn + jg0, &Vts[bs * 4096 + kvdst]);
            gl2lds4 (msrc + (size_t)(it + 2) * 2048 * 8,  (char*)Mb + bs * 2048 + mdst);
        }
        __builtin_amdgcn_sched_barrier(0);

        // ---- compute tile it from buf bc ----
        const int bo = bc * 4096;
        floatx4 sc[2][4];
        __builtin_amdgcn_s_setprio(1);
#pragma unroll
        for (int n0 = 0; n0 < 4; ++n0) {
            const int R = n0 * 16 + l15, xr = R & 7;
            const short8 kb0 = *(const short8*)&Ks[bo + R * 64 + ((quad ^ xr) * 8)];
            const short8 kb1 = *(const short8*)&Ks[bo + R * 64 + (((quad + 4) ^ xr) * 8)];
            sc[0][n0] = __builtin_amdgcn_mfma_f32_16x16x32_bf16(kb0, qf00, z4, 0, 0, 0);
            sc[0][n0] = __builtin_amdgcn_mfma_f32_16x16x32_bf16(kb1, qf01, sc[0][n0], 0, 0, 0);
            sc[1][n0] = __builtin_amdgcn_mfma_f32_16x16x32_bf16(kb0, qf10, z4, 0, 0, 0);
            sc[1][n0] = __builtin_amdgcn_mfma_f32_16x16x32_bf16(kb1, qf11, sc[1][n0], 0, 0, 0);
        }
        __builtin_amdgcn_s_setprio(0);

        // row bit-words for both groups (one ds_read_b64 each; quads broadcast)
        const uint2v row0b = Mb[bc * 256 + wave * 32 + l15];
        const uint2v row1b = Mb[bc * 256 + wave * 32 + 16 + l15];

        unsigned uu[2][4][2];
#pragma unroll
        for (int g = 0; g < 2; ++g) {
            const uint2v rw = g ? row1b : row0b;
#pragma unroll
            for (int n0 = 0; n0 < 4; ++n0) {
                const unsigned selw = (n0 < 2) ? rw.x : rw.y;
                const unsigned nib = (selw >> (qsh + ((n0 & 1) << 4))) & 15u;
                const uint2v mm = Mlut[nib];
                const floatx4 v = sc[g][n0];
                const unsigned u0 = pack_bf(__builtin_amdgcn_exp2f(v[0]),
                                            __builtin_amdgcn_exp2f(v[1])) & mm.x;
                const unsigned u1 = pack_bf(__builtin_amdgcn_exp2f(v[2]),
                                            __builtin_amdgcn_exp2f(v[3])) & mm.y;
                uu[g][n0][0] = u0; uu[g][n0][1] = u1;
            }
        }
        short8 pa00 = pswz(uu[0][0][0], uu[0][0][1], uu[0][1][0], uu[0][1][1]);
        short8 pa01 = pswz(uu[0][2][0], uu[0][2][1], uu[0][3][0], uu[0][3][1]);
        short8 pa10 = pswz(uu[1][0][0], uu[1][0][1], uu[1][1][0], uu[1][1][1]);
        short8 pa11 = pswz(uu[1][2][0], uu[1][2][1], uu[1][3][0], uu[1][3][1]);

        __builtin_amdgcn_s_setprio(1);
        // l accumulation via all-ones B operand (no VALU chain, no shuffles)
        lacc[0] = __builtin_amdgcn_mfma_f32_16x16x32_bf16(pa00, ones8, lacc[0], 0, 0, 0);
        lacc[0] = __builtin_amdgcn_mfma_f32_16x16x32_bf16(pa01, ones8, lacc[0], 0, 0, 0);
        lacc[1] = __builtin_amdgcn_mfma_f32_16x16x32_bf16(pa10, ones8, lacc[1], 0, 0, 0);
        lacc[1] = __builtin_amdgcn_mfma_f32_16x16x32_bf16(pa11, ones8, lacc[1], 0, 0, 0);
#pragma unroll
        for (int n0 = 0; n0 < 4; ++n0) {
            const int R = n0 * 16 + l15, xr = R & 7;
            const short8 vb0 = *(const short8*)&Vts[bo + R * 64 + ((quad ^ xr) * 8)];
            const short8 vb1 = *(const short8*)&Vts[bo + R * 64 + (((quad + 4) ^ xr) * 8)];
            o[0][n0] = __builtin_amdgcn_mfma_f32_16x16x32_bf16(pa00, vb0, o[0][n0], 0, 0, 0);
            o[0][n0] = __builtin_amdgcn_mfma_f32_16x16x32_bf16(pa01, vb1, o[0][n0], 0, 0, 0);
            o[1][n0] = __builtin_amdgcn_mfma_f32_16x16x32_bf16(pa10, vb0, o[1][n0], 0, 0, 0);
            o[1][n0] = __builtin_amdgcn_mfma_f32_16x16x32_bf16(pa11, vb1, o[1][n0], 0, 0, 0);
        }
        __builtin_amdgcn_s_setprio(0);

        bc = (bc == 2) ? 0 : bc + 1;
        bs = (bs == 2) ? 0 : bs + 1;
    }

    // --- epilogue: lacc[g][i] = l[q = g*16 + quad*4 + i] in-lane ---
#pragma unroll
    for (int g = 0; g < 2; ++g) {
#pragma unroll
        for (int i = 0; i < 4; ++i) {
            const float la = 1.f / lacc[g][i];
            const int sA = s0 + wave * 32 + g * 16 + quad * 4 + i;
#pragma unroll
            for (int n0 = 0; n0 < 4; ++n0)
                ctxb[((size_t)sA * B_ + b) * H_ + h * HD_ + n0 * 16 + l15] =
                    f2bf(o[g][n0][i] * la);
        }
    }
}

// ---------------------------------------------------------------------------
extern "C" void kernel_launch(void* const* d_in, const int* in_sizes, int n_in,
                              void* d_out, int out_size, void* d_ws, size_t ws_size,
                              hipStream_t stream)
{
    const float* hidden = (const float*)d_in[0];
    const int*   mask   = (const int*)d_in[1];
    const float* Wqkv   = (const float*)d_in[2];
    const float* bqkv   = (const float*)d_in[3];
    const float* Wd     = (const float*)d_in[4];
    const float* bd     = (const float*)d_in[5];
    float* out = (float*)d_out;

    const size_t HE = (size_t)B_ * NH_ * S_ * HD_;   // 8388608
    short* hBF    = (short*)d_ws;
    short* WqkvBF = hBF + (size_t)S_ * B_ * H_;
    short* WdBF   = WqkvBF + (size_t)3 * H_ * H_;
    short* Qb     = WdBF + (size_t)H_ * H_;
    short* Kb     = Qb + HE;
    short* Vb     = Kb + HE;
    short* Vtb    = Vb + HE;
    short* ctxb   = Vtb + HE;
    // mask bit-words: B*32*2048*8 B = 2 MB -> alias hBF (dead after gemm_qkv;
    // mask_bit launched after it, stream-ordered).
    unsigned long long* mbits = (unsigned long long*)hBF;

    const int nh4 = (S_ * B_ * H_) / 4;   // 2097152
    const int nw4 = (3 * H_ * H_) / 4;    // 786432
    const int nd4 = (H_ * H_) / 4;        // 262144
    hipLaunchKernelGGL(cvt3_kernel, dim3((nh4 + nw4 + nd4) / 256), dim3(256), 0, stream,
                       hidden, hBF, nh4, Wqkv, WqkvBF, nw4, Wd, WdBF, nd4);

    hipLaunchKernelGGL(gemm_qkv_mfma, dim3((3 * H_) / 128, (S_ * B_) / 128), dim3(256), 0, stream,
                       hBF, WqkvBF, bqkv, Qb, Kb, Vb);
    hipLaunchKernelGGL(mask_bit_kernel, dim3(B_ * S_ * (S_ / 256) / 4), dim3(256), 0, stream,
                       mask, mbits);
    hipLaunchKernelGGL(vtrans_kernel, dim3(S_ / 64, B_ * NH_), dim3(256), 0, stream,
                       Vb, Vtb);
    hipLaunchKernelGGL(flash_mfma_kernel, dim3(S_ / 256, B_ * NH_), dim3(512), 0, stream,
                       Qb, Kb, Vtb, mbits, ctxb);
    hipLaunchKernelGGL(gemm_dense_mfma, dim3(H_ / 128, (S_ * B_) / 128), dim3(256), 0, stream,
                       ctxb, WdBF, bd, out);
}

// Round 11
// 330.202 us; speedup vs baseline: 1.0934x; 1.0237x over previous
//
#include <hip/hip_runtime.h>
#include <hip/hip_bf16.h>
#include <math.h>

// S,B,H,NH = 2048,4,1024,16; HD=64
constexpr int S_ = 2048, B_ = 4, H_ = 1024, NH_ = 16, HD_ = 64;

typedef __attribute__((ext_vector_type(8))) short short8;   // 8 bf16 (4 VGPRs)
typedef __attribute__((ext_vector_type(4))) short short4v;  // 4 bf16
typedef __attribute__((ext_vector_type(4))) float floatx4;  // MFMA C/D
typedef __attribute__((ext_vector_type(2))) unsigned uint2v;

static __device__ __forceinline__ short f2bf(float f) {
    union { float f; unsigned u; } v; v.f = f;
    unsigned r = v.u + 0x7FFFu + ((v.u >> 16) & 1u);  // RNE
    return (short)(r >> 16);
}

// pack two f32 -> one u32 of two bf16 (truncation), via v_perm_b32
static __device__ __forceinline__ unsigned pack_bf(float p0, float p1) {
    return __builtin_amdgcn_perm(__float_as_uint(p1), __float_as_uint(p0), 0x07060302u);
}

// async global->LDS; LDS dest = wave-uniform base + lane*size
static __device__ __forceinline__ void gl2lds16(const void* g, void* l) {
    __builtin_amdgcn_global_load_lds(
        (const __attribute__((address_space(1))) void*)g,
        (__attribute__((address_space(3))) void*)l, 16, 0, 0);
}
static __device__ __forceinline__ void gl2lds4(const void* g, void* l) {
    __builtin_amdgcn_global_load_lds(
        (const __attribute__((address_space(1))) void*)g,
        (__attribute__((address_space(3))) void*)l, 4, 0, 0);
}

// P-fragment redistribution (in-register, replaces Ps LDS round-trip).
static __device__ __forceinline__ short8 pswz(unsigned a0, unsigned a1,
                                              unsigned b0, unsigned b1) {
    uint2v r0 = __builtin_amdgcn_permlane32_swap(a0, b0, false, false);
    uint2v s0 = __builtin_amdgcn_permlane16_swap(r0.x, r0.y, false, false);
    uint2v r1 = __builtin_amdgcn_permlane32_swap(a1, b1, false, false);
    uint2v s1 = __builtin_amdgcn_permlane16_swap(r1.x, r1.y, false, false);
    union { unsigned u[4]; short8 s; } o;
    o.u[0] = s0.x;  // W0: t = dq*8 + {0,1}
    o.u[1] = s1.x;  // W1: t = dq*8 + {2,3}
    o.u[2] = s0.y;  // W2: t = dq*8 + {4,5}
    o.u[3] = s1.y;  // W3: t = dq*8 + {6,7}
    return o.s;
}

// spread 16 bits to every 4th bit position of a u64
static __device__ __forceinline__ unsigned long long spread4(unsigned x) {
    unsigned long long s = x;
    s = (s | (s << 24)) & 0x000000FF000000FFull;
    s = (s | (s << 12)) & 0x000F000F000F000Full;
    s = (s | (s << 6))  & 0x0303030303030303ull;
    s = (s | (s << 3))  & 0x1111111111111111ull;
    return s;
}

// ---------------------------------------------------------------------------
// fused fp32 -> bf16 convert for hidden / Wqkv / Wd
// ---------------------------------------------------------------------------
__global__ __launch_bounds__(256) void cvt3_kernel(
    const float* __restrict__ a, short* __restrict__ oa, int na,
    const float* __restrict__ b, short* __restrict__ ob, int nb,
    const float* __restrict__ c, short* __restrict__ oc, int nc)
{
    const int idx = blockIdx.x * 256 + threadIdx.x;
    const float* src; short* dst; int i;
    if (idx < na)            { src = a; dst = oa; i = idx; }
    else if (idx < na + nb)  { src = b; dst = ob; i = idx - na; }
    else                     { src = c; dst = oc; i = idx - na - nb; }
    const float4 v = ((const float4*)src)[i];
    short4v o = { (short)f2bf(v.x), (short)f2bf(v.y), (short)f2bf(v.z), (short)f2bf(v.w) };
    ((short4v*)dst)[i] = o;
}

// ---------------------------------------------------------------------------
// mask int32 -> keep-BITS, layout [b][tblk=32][q=2048] u64 (bit j of word =
// keep for t = tblk*64 + j). int4 per lane (coalesced); 4 ballots + bit
// interleave assemble 4 u64 words; lanes 0..3 store them.
// ---------------------------------------------------------------------------
__global__ __launch_bounds__(256) void mask_bit_kernel(
    const int* __restrict__ m, unsigned long long* __restrict__ mb)
{
    const int wid  = blockIdx.x * 4 + (threadIdx.x >> 6);
    const int lane = threadIdx.x & 63;
    const int b   = wid >> 14;           // 2048 q * 8 seg = 16384 per b
    const int rem = wid & 16383;
    const int q   = rem >> 3;
    const int seg = rem & 7;
    const int4 v = *(const int4*)(m + ((size_t)b * S_ + q) * S_ + seg * 256 + lane * 4);
    const unsigned nib = (v.x ? 0u : 1u) | (v.y ? 0u : 2u) |
                         (v.z ? 0u : 4u) | (v.w ? 0u : 8u);
    const unsigned long long b0 = __ballot((nib & 1u) != 0u);
    const unsigned long long b1 = __ballot((nib & 2u) != 0u);
    const unsigned long long b2 = __ballot((nib & 4u) != 0u);
    const unsigned long long b3 = __ballot((nib & 8u) != 0u);
    if (lane < 4) {
        const int sh = lane * 16;
        const unsigned long long w =
            spread4((unsigned)((b0 >> sh) & 0xFFFFu)) |
            (spread4((unsigned)((b1 >> sh) & 0xFFFFu)) << 1) |
            (spread4((unsigned)((b2 >> sh) & 0xFFFFu)) << 2) |
            (spread4((unsigned)((b3 >> sh) & 0xFFFFu)) << 3);
        mb[((size_t)b * 32 + seg * 4 + lane) * 2048 + q] = w;
    }
}

// ---------------------------------------------------------------------------
// QKV GEMM v4: BK=32 depth-2 counted-vmcnt pipeline + XCD swizzle +
// LDS-transposed epilogue (R10 fix: old epilogue made 32B-segment scalar
// stores -> WRITE_SIZE 110MB for 48MB useful, 2.3x amplification, ~whole
// kernel duration). New: acc -> bf16 C-tile in LDS [128][136] (reuses the
// As/Bs union, +8 pad), then 8-lanes-per-128B-segment coalesced copy-out.
// Each 64-col half-row of the tile is one contiguous 128B run in Qb/Kb/Vb
// (col0 % 128 == 0, head segments 64-wide).
// ---------------------------------------------------------------------------
__global__ __launch_bounds__(256, 3) void gemm_qkv_mfma(
    const short* __restrict__ A, const short* __restrict__ Bw,
    const float* __restrict__ bias,
    short* __restrict__ Qb, short* __restrict__ Kb, short* __restrict__ Vb)
{
    constexpr int K = H_;  // 1024
    __shared__ __align__(16) short SMEM[3 * 4096 * 2];   // As | Bs; reused as C-tile
    short* const As = SMEM;
    short* const Bs = SMEM + 3 * 4096;

    const int t = threadIdx.x;
    const int wave = t >> 6, lane = t & 63;
    const int l15 = lane & 15, quad = lane >> 4;
    const int wm = wave & 1, wn = wave >> 1;
    // XCD swizzle: grid (24,64) = 1536 blocks, 192/XCD = 8 row-panels x 24 cols
    const int L  = blockIdx.y * 24 + blockIdx.x;
    const int n  = L >> 3;
    const int row0 = (((L & 7) << 3) + (n & 7)) * 128;
    const int col0 = (n >> 3) * 128;

    floatx4 acc[4][4];
#pragma unroll
    for (int mi = 0; mi < 4; ++mi)
#pragma unroll
        for (int ni = 0; ni < 4; ++ni)
            acc[mi][ni] = (floatx4){0.f, 0.f, 0.f, 0.f};

    const int c0 = wave * 128 + lane, c1 = c0 + 64;
    const int r0 = c0 >> 2, jg0 = (((c0 & 3) ^ (((r0 & 3) + ((r0 >> 2) & 3)) & 3))) * 8;
    const int r1 = c1 >> 2, jg1 = (((c1 & 3) ^ (((r1 & 3) + ((r1 >> 2) & 3)) & 3))) * 8;
    const int db0 = (wave * 128) * 8;
    const int db1 = db0 + 64 * 8;

    const short* Ar0 = A  + (size_t)(row0 + r0) * K + jg0;
    const short* Ar1 = A  + (size_t)(row0 + r1) * K + jg1;
    const short* Br0 = Bw + (size_t)(col0 + r0) * K + jg0;
    const short* Br1 = Bw + (size_t)(col0 + r1) * K + jg1;

    gl2lds16(Ar0, &As[db0]); gl2lds16(Ar1, &As[db1]);
    gl2lds16(Br0, &Bs[db0]); gl2lds16(Br1, &Bs[db1]);
    __builtin_amdgcn_sched_barrier(0);
    gl2lds16(Ar0 + 32, &As[4096 + db0]); gl2lds16(Ar1 + 32, &As[4096 + db1]);
    gl2lds16(Br0 + 32, &Bs[4096 + db0]); gl2lds16(Br1 + 32, &Bs[4096 + db1]);
    __builtin_amdgcn_sched_barrier(0);

    int bc = 0, bs = 2;
#pragma unroll 1
    for (int it = 0; it < 32; ++it) {
        if (it < 31) { asm volatile("s_waitcnt vmcnt(4)" ::: "memory"); }
        else         { asm volatile("s_waitcnt vmcnt(0)" ::: "memory"); }
        __builtin_amdgcn_s_barrier();
        __builtin_amdgcn_sched_barrier(0);

        if (it < 30) {
            const int ko = (it + 2) * 32;
            gl2lds16(Ar0 + ko, &As[bs * 4096 + db0]);
            gl2lds16(Ar1 + ko, &As[bs * 4096 + db1]);
            gl2lds16(Br0 + ko, &Bs[bs * 4096 + db0]);
            gl2lds16(Br1 + ko, &Bs[bs * 4096 + db1]);
        }
        __builtin_amdgcn_sched_barrier(0);

        const int bo = bc * 4096;
        short8 af[4], bfr[4];
#pragma unroll
        for (int mi = 0; mi < 4; ++mi) {
            const int R = wm * 64 + mi * 16 + l15;
            const int sel = quad ^ (((R & 3) + ((R >> 2) & 3)) & 3);
            af[mi] = *(const short8*)&As[bo + R * 32 + sel * 8];
        }
#pragma unroll
        for (int ni = 0; ni < 4; ++ni) {
            const int R = wn * 64 + ni * 16 + l15;
            const int sel = quad ^ (((R & 3) + ((R >> 2) & 3)) & 3);
            bfr[ni] = *(const short8*)&Bs[bo + R * 32 + sel * 8];
        }
        __builtin_amdgcn_s_setprio(1);
#pragma unroll
        for (int mi = 0; mi < 4; ++mi)
#pragma unroll
            for (int ni = 0; ni < 4; ++ni)
                acc[mi][ni] = __builtin_amdgcn_mfma_f32_16x16x32_bf16(
                    af[mi], bfr[ni], acc[mi][ni], 0, 0, 0);
        __builtin_amdgcn_s_setprio(0);

        bc = (bc == 2) ? 0 : bc + 1;
        bs = (bs == 2) ? 0 : bs + 1;
    }

    // ---- epilogue v2: acc -> LDS bf16 C-tile [128][136] -> coalesced out ----
    __syncthreads();   // all frag reads complete before As/Bs overwrite
#pragma unroll
    for (int ni = 0; ni < 4; ++ni) {
        const int gc = col0 + wn * 64 + ni * 16 + l15;
        const int hh = gc / 192;
        const int rem = gc - hh * 192;
        const int which = rem >> 6;
        const float scale = (which == 0) ? 0.1803368801111204f : 1.0f;
        const float bv = bias[gc];
        const int cl = wn * 64 + ni * 16 + l15;
#pragma unroll
        for (int mi = 0; mi < 4; ++mi)
#pragma unroll
            for (int i = 0; i < 4; ++i) {
                const int rl = wm * 64 + mi * 16 + quad * 4 + i;
                SMEM[rl * 136 + cl] = f2bf((acc[mi][ni][i] + bv) * scale);
            }
    }
    __syncthreads();
    // copy-out: 8 lanes per 128B segment; 256 segments = 128 rows x 2 halves
    const int chunk = t & 7;
#pragma unroll
    for (int r = 0; r < 8; ++r) {
        const int gs = r * 32 + (t >> 3);
        const int row = gs >> 1, half = gs & 1;
        const int gc0 = col0 + half * 64;
        const int hh = gc0 / 192;
        const int rem = gc0 - hh * 192;
        const int which = rem >> 6;
        const int gr = row0 + row;
        const int s = gr >> 2, bb = gr & 3;      // row = s*B + b
        const size_t off = (((size_t)(bb * NH_ + hh)) * S_ + s) * HD_ + chunk * 8;
        const short8 v = *(const short8*)&SMEM[row * 136 + half * 64 + chunk * 8];
        if (which == 0)      *(short8*)(Qb + off) = v;
        else if (which == 1) *(short8*)(Kb + off) = v;
        else                 *(short8*)(Vb + off) = v;
    }
}

// ---------------------------------------------------------------------------
// V transpose: Vb [bh][s][d] -> Vtb [bh][d][s], 64x64 tiles via swizzled LDS.
// ---------------------------------------------------------------------------
__global__ __launch_bounds__(256) void vtrans_kernel(
    const short* __restrict__ Vb, short* __restrict__ Vtb)
{
    const int bh = blockIdx.y;
    const int s0 = blockIdx.x * 64;
    __shared__ __align__(16) short T[64 * 64];
    const int t = threadIdx.x;

#pragma unroll
    for (int it = 0; it < 2; ++it) {
        const int c = t + it * 256;
        const int r = c >> 3, jp = c & 7;
        const int jg = jp ^ ((r >> 3) & 7);
        *(short8*)&T[r * 64 + jp * 8] =
            *(const short8*)(Vb + ((size_t)bh * S_ + s0 + r) * HD_ + jg * 8);
    }
    __syncthreads();

#pragma unroll
    for (int it = 0; it < 2; ++it) {
        const int c = t + it * 256;
        const int d = c >> 3, sg = (c & 7) * 8;
        short8 v;
#pragma unroll
        for (int k = 0; k < 8; ++k) {
            const int r = sg + k;
            v[k] = T[r * 64 + (((d >> 3) ^ ((r >> 3) & 7)) * 8) + (d & 7)];
        }
        *(short8*)(Vtb + ((size_t)bh * HD_ + d) * S_ + s0 + sg) = v;
    }
}

// ---------------------------------------------------------------------------
// Dense GEMM v3: BK=32 depth-2 counted-vmcnt pipeline + XCD swizzle.
// (fp32 stores are 64B full-line-aligned segments -- no write amplification,
// epilogue left direct.)
// ---------------------------------------------------------------------------
__global__ __launch_bounds__(256, 3) void gemm_dense_mfma(
    const short* __restrict__ A, const short* __restrict__ Bw,
    const float* __restrict__ bias, float* __restrict__ out)
{
    constexpr int K = H_;  // 1024
    __shared__ __align__(16) short As[3 * 4096];
    __shared__ __align__(16) short Bs[3 * 4096];

    const int t = threadIdx.x;
    const int wave = t >> 6, lane = t & 63;
    const int l15 = lane & 15, quad = lane >> 4;
    const int wm = wave & 1, wn = wave >> 1;
    // XCD swizzle: grid (8,64) = 512 blocks, 64/XCD = 8 row-panels x 8 cols
    const int L  = blockIdx.y * 8 + blockIdx.x;
    const int n  = L >> 3;
    const int row0 = (((L & 7) << 3) + (n & 7)) * 128;
    const int col0 = (n >> 3) * 128;

    floatx4 acc[4][4];
#pragma unroll
    for (int mi = 0; mi < 4; ++mi)
#pragma unroll
        for (int ni = 0; ni < 4; ++ni)
            acc[mi][ni] = (floatx4){0.f, 0.f, 0.f, 0.f};

    const int c0 = wave * 128 + lane, c1 = c0 + 64;
    const int r0 = c0 >> 2, jg0 = (((c0 & 3) ^ (((r0 & 3) + ((r0 >> 2) & 3)) & 3))) * 8;
    const int r1 = c1 >> 2, jg1 = (((c1 & 3) ^ (((r1 & 3) + ((r1 >> 2) & 3)) & 3))) * 8;
    const int db0 = (wave * 128) * 8;
    const int db1 = db0 + 64 * 8;

    const short* Ar0 = A  + (size_t)(row0 + r0) * K + jg0;
    const short* Ar1 = A  + (size_t)(row0 + r1) * K + jg1;
    const short* Br0 = Bw + (size_t)(col0 + r0) * K + jg0;
    const short* Br1 = Bw + (size_t)(col0 + r1) * K + jg1;

    gl2lds16(Ar0, &As[db0]); gl2lds16(Ar1, &As[db1]);
    gl2lds16(Br0, &Bs[db0]); gl2lds16(Br1, &Bs[db1]);
    __builtin_amdgcn_sched_barrier(0);
    gl2lds16(Ar0 + 32, &As[4096 + db0]); gl2lds16(Ar1 + 32, &As[4096 + db1]);
    gl2lds16(Br0 + 32, &Bs[4096 + db0]); gl2lds16(Br1 + 32, &Bs[4096 + db1]);
    __builtin_amdgcn_sched_barrier(0);

    int bc = 0, bs = 2;
#pragma unroll 1
    for (int it = 0; it < 32; ++it) {
        if (it < 31) { asm volatile("s_waitcnt vmcnt(4)" ::: "memory"); }
        else         { asm volatile("s_waitcnt vmcnt(0)" ::: "memory"); }
        __builtin_amdgcn_s_barrier();
        __builtin_amdgcn_sched_barrier(0);

        if (it < 30) {
            const int ko = (it + 2) * 32;
            gl2lds16(Ar0 + ko, &As[bs * 4096 + db0]);
            gl2lds16(Ar1 + ko, &As[bs * 4096 + db1]);
            gl2lds16(Br0 + ko, &Bs[bs * 4096 + db0]);
            gl2lds16(Br1 + ko, &Bs[bs * 4096 + db1]);
        }
        __builtin_amdgcn_sched_barrier(0);

        const int bo = bc * 4096;
        short8 af[4], bfr[4];
#pragma unroll
        for (int mi = 0; mi < 4; ++mi) {
            const int R = wm * 64 + mi * 16 + l15;
            const int sel = quad ^ (((R & 3) + ((R >> 2) & 3)) & 3);
            af[mi] = *(const short8*)&As[bo + R * 32 + sel * 8];
        }
#pragma unroll
        for (int ni = 0; ni < 4; ++ni) {
            const int R = wn * 64 + ni * 16 + l15;
            const int sel = quad ^ (((R & 3) + ((R >> 2) & 3)) & 3);
            bfr[ni] = *(const short8*)&Bs[bo + R * 32 + sel * 8];
        }
        __builtin_amdgcn_s_setprio(1);
#pragma unroll
        for (int mi = 0; mi < 4; ++mi)
#pragma unroll
            for (int ni = 0; ni < 4; ++ni)
                acc[mi][ni] = __builtin_amdgcn_mfma_f32_16x16x32_bf16(
                    af[mi], bfr[ni], acc[mi][ni], 0, 0, 0);
        __builtin_amdgcn_s_setprio(0);

        bc = (bc == 2) ? 0 : bc + 1;
        bs = (bs == 2) ? 0 : bs + 1;
    }

#pragma unroll
    for (int ni = 0; ni < 4; ++ni) {
        const int gc = col0 + wn * 64 + ni * 16 + l15;
        const float bv = bias[gc];
#pragma unroll
        for (int mi = 0; mi < 4; ++mi)
#pragma unroll
            for (int i = 0; i < 4; ++i) {
                const int gr = row0 + wm * 64 + mi * 16 + quad * 4 + i;
                out[(size_t)gr * H_ + gc] = acc[mi][ni][i] + bv;
            }
    }
}

// ---------------------------------------------------------------------------
// Flash attention v8 (unchanged -- verified 90.4us, VGPR 64, no spill,
// MfmaUtil 35/VALU 50 at 4 waves/SIMD: issue-bound).
// ---------------------------------------------------------------------------
__global__ __launch_bounds__(512, 4) void flash_mfma_kernel(
    const short* __restrict__ Qb, const short* __restrict__ Kb,
    const short* __restrict__ Vtb, const unsigned long long* __restrict__ mbits,
    short* __restrict__ ctxb)
{
    const int bh = blockIdx.y;
    const int b  = bh >> 4;          // / NH_
    const int h  = bh & 15;          // % NH_
    const int s0 = blockIdx.x * 256;

    const int tdx  = threadIdx.x;
    const int wave = tdx >> 6;       // 0..7
    const int lane = tdx & 63;
    const int l15  = lane & 15;
    const int quad = lane >> 4;

    __shared__ __align__(16) short Ks [3 * 4096];   // [buf][key64][d64]
    __shared__ __align__(16) short Vts[3 * 4096];   // [buf][d64][key64]
    __shared__ __align__(16) uint2v Mb[3 * 256];    // [buf][q256] bit-rows (u64)
    __shared__ __align__(16) uint2v Mlut[16];       // nib -> {m0, m1}

    // LUT init (before any staging; __syncthreads here is pre-pipeline)
    if (tdx < 16) {
        const unsigned m0 = ((tdx & 1) ? 0xFFFFu : 0u) | ((tdx & 2) ? 0xFFFF0000u : 0u);
        const unsigned m1 = ((tdx & 4) ? 0xFFFFu : 0u) | ((tdx & 8) ? 0xFFFF0000u : 0u);
        Mlut[tdx] = (uint2v){m0, m1};
    }
    __syncthreads();

    // Q fragments: wave owns q rows [s0+wave*32, +32), 2 groups of 16
    const short* Qg = Qb + ((size_t)bh * S_ + s0 + wave * 32 + l15) * HD_;
    short8 qf00 = *(const short8*)(Qg + quad * 8);
    short8 qf01 = *(const short8*)(Qg + 32 + quad * 8);
    short8 qf10 = *(const short8*)(Qg + 16 * HD_ + quad * 8);
    short8 qf11 = *(const short8*)(Qg + 16 * HD_ + 32 + quad * 8);

    const short* Kbase  = Kb  + (size_t)bh * S_ * HD_;
    const short* Vtbase = Vtb + (size_t)bh * HD_ * S_;

    floatx4 o[2][4];
    floatx4 lacc[2];
#pragma unroll
    for (int g = 0; g < 2; ++g) {
        lacc[g] = (floatx4){0.f, 0.f, 0.f, 0.f};
#pragma unroll
        for (int n0 = 0; n0 < 4; ++n0) o[g][n0] = (floatx4){0.f, 0.f, 0.f, 0.f};
    }
    const short8 ones8 = {(short)0x3F80, (short)0x3F80, (short)0x3F80, (short)0x3F80,
                          (short)0x3F80, (short)0x3F80, (short)0x3F80, (short)0x3F80};

    // K/V staging geometry: 512 chunks/tile, 64 per wave
    const int c0 = wave * 64 + lane;
    const int r0 = c0 >> 3, jg0 = ((c0 & 7) ^ (r0 & 7)) * 8;
    const int kvdst = wave * 512;                     // + buf*4096 (elems)
    // M staging: wave stages its 32 rows (256 B) linearly, 4 B/lane
    const char* msrc = (const char*)mbits + ((size_t)(b * 32) * 2048 + s0 + wave * 32) * 8 + lane * 4;
    const int   mdst = wave * 256;                    // bytes; + buf*2048

    // prologue: stage(0) -> buf0, stage(1) -> buf1 (FIFO blocks of 3)
    gl2lds16(Kbase  + (size_t)r0 * HD_ + jg0, &Ks[kvdst]);
    gl2lds16(Vtbase + (size_t)r0 * S_ + jg0,  &Vts[kvdst]);
    gl2lds4 (msrc,                            (char*)Mb + mdst);
    __builtin_amdgcn_sched_barrier(0);
    gl2lds16(Kbase  + (size_t)(64 + r0) * HD_ + jg0, &Ks[4096 + kvdst]);
    gl2lds16(Vtbase + (size_t)r0 * S_ + 64 + jg0,    &Vts[4096 + kvdst]);
    gl2lds4 (msrc + 2048 * 8,                        (char*)Mb + 2048 + mdst);
    __builtin_amdgcn_sched_barrier(0);

    const floatx4 z4 = {0.f, 0.f, 0.f, 0.f};
    const int qsh = quad * 4;
    int bc = 0, bs = 2;   // compute / stage buffer indices

#pragma unroll 1
    for (int it = 0; it < 32; ++it) {
        // counted wait: stage(it) retired; stage(it+1) [3 ops] may remain
        if (it < 31) { asm volatile("s_waitcnt vmcnt(3)" ::: "memory"); }
        else         { asm volatile("s_waitcnt vmcnt(0)" ::: "memory"); }
        __builtin_amdgcn_s_barrier();
        __builtin_amdgcn_sched_barrier(0);

        // stage tile it+2 into buf bs (FIFO block of 3)
        if (it < 30) {
            const size_t tn = (size_t)(it + 2) * 64;
            gl2lds16(Kbase  + (tn + r0) * HD_ + jg0,      &Ks[bs * 4096 + kvdst]);
            gl2lds16(Vtbase + (size_t)r0 * S_ + tn + jg0, &Vts[bs * 4096 + kvdst]);
            gl2lds4 (msrc + (size_t)(it + 2) * 2048 * 8,  (char*)Mb + bs * 2048 + mdst);
        }
        __builtin_amdgcn_sched_barrier(0);

        // ---- compute tile it from buf bc ----
        const int bo = bc * 4096;
        floatx4 sc[2][4];
        __builtin_amdgcn_s_setprio(1);
#pragma unroll
        for (int n0 = 0; n0 < 4; ++n0) {
            const int R = n0 * 16 + l15, xr = R & 7;
            const short8 kb0 = *(const short8*)&Ks[bo + R * 64 + ((quad ^ xr) * 8)];
            const short8 kb1 = *(const short8*)&Ks[bo + R * 64 + (((quad + 4) ^ xr) * 8)];
            sc[0][n0] = __builtin_amdgcn_mfma_f32_16x16x32_bf16(kb0, qf00, z4, 0, 0, 0);
            sc[0][n0] = __builtin_amdgcn_mfma_f32_16x16x32_bf16(kb1, qf01, sc[0][n0], 0, 0, 0);
            sc[1][n0] = __builtin_amdgcn_mfma_f32_16x16x32_bf16(kb0, qf10, z4, 0, 0, 0);
            sc[1][n0] = __builtin_amdgcn_mfma_f32_16x16x32_bf16(kb1, qf11, sc[1][n0], 0, 0, 0);
        }
        __builtin_amdgcn_s_setprio(0);

        // row bit-words for both groups (one ds_read_b64 each; quads broadcast)
        const uint2v row0b = Mb[bc * 256 + wave * 32 + l15];
        const uint2v row1b = Mb[bc * 256 + wave * 32 + 16 + l15];

        unsigned uu[2][4][2];
#pragma unroll
        for (int g = 0; g < 2; ++g) {
            const uint2v rw = g ? row1b : row0b;
#pragma unroll
            for (int n0 = 0; n0 < 4; ++n0) {
                const unsigned selw = (n0 < 2) ? rw.x : rw.y;
                const unsigned nib = (selw >> (qsh + ((n0 & 1) << 4))) & 15u;
                const uint2v mm = Mlut[nib];
                const floatx4 v = sc[g][n0];
                const unsigned u0 = pack_bf(__builtin_amdgcn_exp2f(v[0]),
                                            __builtin_amdgcn_exp2f(v[1])) & mm.x;
                const unsigned u1 = pack_bf(__builtin_amdgcn_exp2f(v[2]),
                                            __builtin_amdgcn_exp2f(v[3])) & mm.y;
                uu[g][n0][0] = u0; uu[g][n0][1] = u1;
            }
        }
        short8 pa00 = pswz(uu[0][0][0], uu[0][0][1], uu[0][1][0], uu[0][1][1]);
        short8 pa01 = pswz(uu[0][2][0], uu[0][2][1], uu[0][3][0], uu[0][3][1]);
        short8 pa10 = pswz(uu[1][0][0], uu[1][0][1], uu[1][1][0], uu[1][1][1]);
        short8 pa11 = pswz(uu[1][2][0], uu[1][2][1], uu[1][3][0], uu[1][3][1]);

        __builtin_amdgcn_s_setprio(1);
        // l accumulation via all-ones B operand (no VALU chain, no shuffles)
        lacc[0] = __builtin_amdgcn_mfma_f32_16x16x32_bf16(pa00, ones8, lacc[0], 0, 0, 0);
        lacc[0] = __builtin_amdgcn_mfma_f32_16x16x32_bf16(pa01, ones8, lacc[0], 0, 0, 0);
        lacc[1] = __builtin_amdgcn_mfma_f32_16x16x32_bf16(pa10, ones8, lacc[1], 0, 0, 0);
        lacc[1] = __builtin_amdgcn_mfma_f32_16x16x32_bf16(pa11, ones8, lacc[1], 0, 0, 0);
#pragma unroll
        for (int n0 = 0; n0 < 4; ++n0) {
            const int R = n0 * 16 + l15, xr = R & 7;
            const short8 vb0 = *(const short8*)&Vts[bo + R * 64 + ((quad ^ xr) * 8)];
            const short8 vb1 = *(const short8*)&Vts[bo + R * 64 + (((quad + 4) ^ xr) * 8)];
            o[0][n0] = __builtin_amdgcn_mfma_f32_16x16x32_bf16(pa00, vb0, o[0][n0], 0, 0, 0);
            o[0][n0] = __builtin_amdgcn_mfma_f32_16x16x32_bf16(pa01, vb1, o[0][n0], 0, 0, 0);
            o[1][n0] = __builtin_amdgcn_mfma_f32_16x16x32_bf16(pa10, vb0, o[1][n0], 0, 0, 0);
            o[1][n0] = __builtin_amdgcn_mfma_f32_16x16x32_bf16(pa11, vb1, o[1][n0], 0, 0, 0);
        }
        __builtin_amdgcn_s_setprio(0);

        bc = (bc == 2) ? 0 : bc + 1;
        bs = (bs == 2) ? 0 : bs + 1;
    }

    // --- epilogue: lacc[g][i] = l[q = g*16 + quad*4 + i] in-lane ---
#pragma unroll
    for (int g = 0; g < 2; ++g) {
#pragma unroll
        for (int i = 0; i < 4; ++i) {
            const float la = 1.f / lacc[g][i];
            const int sA = s0 + wave * 32 + g * 16 + quad * 4 + i;
#pragma unroll
            for (int n0 = 0; n0 < 4; ++n0)
                ctxb[((size_t)sA * B_ + b) * H_ + h * HD_ + n0 * 16 + l15] =
                    f2bf(o[g][n0][i] * la);
        }
    }
}

// ---------------------------------------------------------------------------
extern "C" void kernel_launch(void* const* d_in, const int* in_sizes, int n_in,
                              void* d_out, int out_size, void* d_ws, size_t ws_size,
                              hipStream_t stream)
{
    const float* hidden = (const float*)d_in[0];
    const int*   mask   = (const int*)d_in[1];
    const float* Wqkv   = (const float*)d_in[2];
    const float* bqkv   = (const float*)d_in[3];
    const float* Wd     = (const float*)d_in[4];
    const float* bd     = (const float*)d_in[5];
    float* out = (float*)d_out;

    const size_t HE = (size_t)B_ * NH_ * S_ * HD_;   // 8388608
    short* hBF    = (short*)d_ws;
    short* WqkvBF = hBF + (size_t)S_ * B_ * H_;
    short* WdBF   = WqkvBF + (size_t)3 * H_ * H_;
    short* Qb     = WdBF + (size_t)H_ * H_;
    short* Kb     = Qb + HE;
    short* Vb     = Kb + HE;
    short* Vtb    = Vb + HE;
    short* ctxb   = Vtb + HE;
    // mask bit-words: B*32*2048*8 B = 2 MB -> alias hBF (dead after gemm_qkv;
    // mask_bit launched after it, stream-ordered).
    unsigned long long* mbits = (unsigned long long*)hBF;

    const int nh4 = (S_ * B_ * H_) / 4;   // 2097152
    const int nw4 = (3 * H_ * H_) / 4;    // 786432
    const int nd4 = (H_ * H_) / 4;        // 262144
    hipLaunchKernelGGL(cvt3_kernel, dim3((nh4 + nw4 + nd4) / 256), dim3(256), 0, stream,
                       hidden, hBF, nh4, Wqkv, WqkvBF, nw4, Wd, WdBF, nd4);

    hipLaunchKernelGGL(gemm_qkv_mfma, dim3((3 * H_) / 128, (S_ * B_) / 128), dim3(256), 0, stream,
                       hBF, WqkvBF, bqkv, Qb, Kb, Vb);
    hipLaunchKernelGGL(mask_bit_kernel, dim3(B_ * S_ * (S_ / 256) / 4), dim3(256), 0, stream,
                       mask, mbits);
    hipLaunchKernelGGL(vtrans_kernel, dim3(S_ / 64, B_ * NH_), dim3(256), 0, stream,
                       Vb, Vtb);
    hipLaunchKernelGGL(flash_mfma_kernel, dim3(S_ / 256, B_ * NH_), dim3(512), 0, stream,
                       Qb, Kb, Vtb, mbits, ctxb);
    hipLaunchKernelGGL(gemm_dense_mfma, dim3(H_ / 128, (S_ * B_) / 128), dim3(256), 0, stream,
                       ctxb, WdBF, bd, out);
}